// Round 8
// baseline (355.693 us; speedup 1.0000x reference)
//
#include <hip/hip_runtime.h>
#include <cstdint>

// Problem constants (fixed by the reference): B=8, N=16384, D=64, P=100.
#define NB    8
#define NN    16384
#define ND    64
#define NP    100
#define NPP   128          // theta rows padded (zeros) for MFMA K/N tiling
#define ST    1024         // sort threads per block (16 waves)
#define SE    16           // elements per sort thread (16384/1024)
#define TROW  72           // padded LDS row stride (ushorts) for project tiles

typedef __attribute__((ext_vector_type(8))) short short8;   // 8 bf16 (4 VGPRs)
typedef __attribute__((ext_vector_type(4))) float f32x4;    // MFMA C/D

// ---------- bf16 convert (RNE) ----------
__device__ __forceinline__ short bf16c(float f) {
  uint32_t u = __float_as_uint(f);
  u = u + 0x7FFFu + ((u >> 16) & 1u);
  return (short)(u >> 16);
}
__device__ __forceinline__ uint32_t bf16pk(float a, float b) {
  return (uint32_t)(ushort)bf16c(a) | ((uint32_t)(ushort)bf16c(b) << 16);
}

// ---------- sortable-key transforms ----------
__device__ __forceinline__ uint32_t f2s_u(uint32_t s) {
  return s ^ (((uint32_t)((int32_t)s >> 31)) | 0x80000000u);
}
__device__ __forceinline__ float s2f(uint32_t u) {
  uint32_t m = (u & 0x80000000u) ? 0x80000000u : 0xFFFFFFFFu;
  return __uint_as_float(u ^ m);
}

// LDS bank swizzle on word index (16B-contiguity-preserving)
__device__ __forceinline__ uint32_t swz(uint32_t w) {
  return w ^ ((w >> 3) & 0x1Cu);
}

// One LSD radix pass on 3-bit digit at shift sh, stable, in-place in S[16384].
// 16 waves: per-wave packed scan + single-wave 64-entry block scan in WG.
// NOTE: the single-wave scan + barrier is CHEAPER than a redundant all-wave
// shuffle scan (measured: +9% regression) because __shfl -> ds_bpermute
// rides the LDS pipe on CDNA.
// Register budget note: pre-scan histogram words are recomputed from lo/hi
// at the use site instead of being held in o[4] (peak live state must fit
// 64 VGPRs: k[16]+ys[16]+xs[16] of the caller + pass workings).
__device__ __forceinline__ void radix_pass(uint32_t (&k)[SE], uint32_t* S,
                                           uint32_t* WG, int tid, int sh,
                                           bool first) {
  const int lane = tid & 63;
  const int wave = tid >> 6;

  if (!first) {
#pragma unroll
    for (int q = 0; q < 4; q++) {
      uint32_t wb = ((uint32_t)tid << 4) + ((uint32_t)q << 2);
      uint4 v = *(const uint4*)(S + (wb ^ ((wb >> 3) & 0x1Cu)));
      k[4 * q + 0] = v.x; k[4 * q + 1] = v.y;
      k[4 * q + 2] = v.z; k[4 * q + 3] = v.w;
    }
  }

  // per-thread digit histogram packed 8 x 8-bit (counts <= 16)
  uint64_t c = 0;
#pragma unroll
  for (int e = 0; e < SE; e++) {
    uint32_t d = (k[e] >> sh) & 7u;
    c += 1ull << (d << 3);
  }

  uint32_t lo = (uint32_t)c, hi = (uint32_t)(c >> 32);
  uint32_t h[4];
  h[0] = (lo & 0xFFu) | ((lo & 0xFF00u) << 8);
  h[1] = ((lo >> 16) & 0xFFu) | ((lo >> 24) << 16);
  h[2] = (hi & 0xFFu) | ((hi & 0xFF00u) << 8);
  h[3] = ((hi >> 16) & 0xFFu) | ((hi >> 24) << 16);

  // wave-level inclusive scan of packed (2x16-bit) counts
#pragma unroll
  for (int off = 1; off <= 32; off <<= 1) {
#pragma unroll
    for (int i = 0; i < 4; i++) {
      uint32_t t = __shfl_up(h[i], (unsigned)off, 64);
      if (lane >= off) h[i] += t;
    }
  }

  if (lane == 63) {
#pragma unroll
    for (int i = 0; i < 4; i++) WG[(wave << 2) + i] = h[i];
  }
  __syncthreads();

  // block scan across 16 waves x 4 packed words (64 entries, one wave)
  if (tid < 64) {
    uint32_t v = WG[tid];
    uint32_t own = v;
#pragma unroll
    for (int off = 4; off <= 32; off <<= 1) {
      uint32_t t = __shfl_up(v, (unsigned)off, 64);
      if (tid >= off) v += t;
    }
    uint32_t wexcl = v - own;                       // excl across waves, same word
    uint32_t grand = __shfl(v, 60 + (tid & 3), 64); // wave-15 inclusive = totals
    uint32_t gl = grand & 0xFFFFu, gh = grand >> 16;
    uint32_t ps = gl + gh, pincl = ps;
#pragma unroll
    for (int off = 1; off <= 2; off <<= 1) {
      uint32_t t = __shfl_up(pincl, (unsigned)off, 64);
      if ((tid & 3) >= off) pincl += t;
    }
    uint32_t pexcl = pincl - ps;                    // digit base for this word pair
    uint32_t g0 = pexcl + (wexcl & 0xFFFFu);
    uint32_t g1 = pexcl + gl + (wexcl >> 16);
    WG[tid] = g0 | (g1 << 16);
  }
  __syncthreads();

  // exclusive within-thread base: WG + (inclusive h - own pre-scan counts),
  // pre-scan words recomputed from lo/hi (saves 4 live VGPRs across the scan)
  uint32_t p0 = WG[(wave << 2) + 0] + h[0] - ((lo & 0xFFu) | ((lo & 0xFF00u) << 8));
  uint32_t p1 = WG[(wave << 2) + 1] + h[1] - (((lo >> 16) & 0xFFu) | ((lo >> 24) << 16));
  uint32_t p2 = WG[(wave << 2) + 2] + h[2] - ((hi & 0xFFu) | ((hi & 0xFF00u) << 8));
  uint32_t p3 = WG[(wave << 2) + 3] + h[3] - (((hi >> 16) & 0xFFu) | ((hi >> 24) << 16));
  uint64_t pc0 = (uint64_t)p0 | ((uint64_t)p1 << 32);
  uint64_t pc1 = (uint64_t)p2 | ((uint64_t)p3 << 32);

#pragma unroll
  for (int e = 0; e < SE; e++) {
    uint32_t d = (k[e] >> sh) & 7u;
    uint32_t s16 = (d & 3u) << 4;
    bool lo4 = d < 4u;
    uint64_t t = lo4 ? pc0 : pc1;
    uint32_t pos = (uint32_t)(t >> s16) & 0xFFFFu;
    uint64_t inc = 1ull << s16;
    pc0 += lo4 ? inc : 0ull;
    pc1 += lo4 ? 0ull : inc;
    S[swz(pos)] = k[e];
  }
  __syncthreads();
}

__device__ __forceinline__ void radix18(uint32_t (&k)[SE], uint32_t* S,
                                        uint32_t* WG, int tid) {
  bool first = true;
  for (int sh = 14; sh < 32; sh += 3) {
    radix_pass(k, S, WG, tid, sh, first);
    first = false;
  }
}

// ---------- kernel 1: normalize theta -> bf16 thb [p][d] AND thbT [d][p] ----
__global__ void normalize_theta(const float* __restrict__ theta,
                                ushort* __restrict__ thb,
                                ushort* __restrict__ thbT) {
  const int p = blockIdx.x, t = threadIdx.x;
  ushort v16 = 0;
  if (p < NP) {
    float v = theta[p * ND + t];
    float ss = v * v;
#pragma unroll
    for (int off = 32; off >= 1; off >>= 1) ss += __shfl_xor(ss, off, 64);
    v16 = (ushort)bf16c(v * rsqrtf(ss));
  }
  thb[p * ND + t] = v16;
  thbT[t * NPP + p] = v16;
}

// ---------- kernel 2: MFMA projection (x AND y per block, LDS-staged) ------
// Stage the block's 64x64 fp32 tiles of x and y into LDS as bf16 via fully
// coalesced global loads (1KB/instr), then read MFMA A-fragments with
// ds_read_b128 (72-ushort padded rows -> 2-way bank aliasing = free).
__global__ __launch_bounds__(256) void project_mfma(
    const float* __restrict__ x, const float* __restrict__ y,
    const ushort* __restrict__ thb, float* __restrict__ xp,
    float* __restrict__ yp) {
  __shared__ ushort XT[64 * TROW];
  __shared__ ushort YT[64 * TROW];
  const int tid  = threadIdx.x;
  const int lane = tid & 63;
  const int quad = lane >> 4;
  const int mloc = lane & 15;
  const int wave = tid >> 6;

  const int m0 = blockIdx.x * 64 + wave * 16;   // 2048 blocks, 64 rows each
  const int b  = m0 >> 14;
  const int n0 = m0 & (NN - 1);

  // --- stage: 64 rows x 64 cols, 1024 float4 per matrix, 4 per thread ---
  {
    const float4* gx = (const float4*)(x + (long)blockIdx.x * 64 * ND);
    const float4* gy = (const float4*)(y + (long)blockIdx.x * 64 * ND);
#pragma unroll
    for (int i = 0; i < 4; i++) {
      const int f4 = tid + 256 * i;        // 0..1023
      const int row = f4 >> 4;             // 16 float4 per row
      const int c4  = f4 & 15;
      float4 vx = gx[f4];
      float4 vy = gy[f4];
      uint2 px, py;
      px.x = bf16pk(vx.x, vx.y); px.y = bf16pk(vx.z, vx.w);
      py.x = bf16pk(vy.x, vy.y); py.y = bf16pk(vy.z, vy.w);
      const int us = row * TROW + c4 * 4;  // ushort index, 8B-aligned
      *(uint2*)(XT + us) = px;
      *(uint2*)(YT + us) = py;
    }
  }
  __syncthreads();

  // --- fragments from LDS ---
  const int fr = wave * 16 + mloc;         // row within block tile
  const short8 ax0 = *(const short8*)(XT + fr * TROW + quad * 8);
  const short8 ax1 = *(const short8*)(XT + fr * TROW + 32 + quad * 8);
  const short8 ay0 = *(const short8*)(YT + fr * TROW + quad * 8);
  const short8 ay1 = *(const short8*)(YT + fr * TROW + 32 + quad * 8);

  const f32x4 zero = {0.f, 0.f, 0.f, 0.f};
#pragma unroll
  for (int t = 0; t < 7; t++) {
    const int p = t * 16 + mloc;
    const short8 b0 = *(const short8*)(thb + p * ND + quad * 8);
    const short8 b1 = *(const short8*)(thb + p * ND + 32 + quad * 8);
    f32x4 accx = __builtin_amdgcn_mfma_f32_16x16x32_bf16(ax0, b0, zero, 0, 0, 0);
    accx = __builtin_amdgcn_mfma_f32_16x16x32_bf16(ax1, b1, accx, 0, 0, 0);
    f32x4 accy = __builtin_amdgcn_mfma_f32_16x16x32_bf16(ay0, b0, zero, 0, 0, 0);
    accy = __builtin_amdgcn_mfma_f32_16x16x32_bf16(ay1, b1, accy, 0, 0, 0);
    if (t < 6 || mloc < (NP - 96)) {
      const long off = ((long)b * NP + p) * NN + n0 + quad * 4;
      *(f32x4*)(xp + off) = accx;   // rows quad*4+r are consecutive n -> float4
      *(f32x4*)(yp + off) = accy;
    }
  }
}

// ---------- kernel 3: per-(b,p) radix-sort y, rank x, write diff ----------
// x_proj values are kept in registers from the key-build phase; the final
// phase positions (tid<<4 + 4q+i) coincide with the key-build positions,
// so no tail re-read of xp is needed (bit-identical subtraction).
__global__ __launch_bounds__(ST, 4) void sort_diff_kernel(
    const float* __restrict__ xp, float* __restrict__ yp) {
  __shared__ uint32_t S[NN];    // 64 KB
  __shared__ uint32_t WG[64];
  const int tid = threadIdx.x;
  const long sbase = (long)blockIdx.x * NN;
  uint32_t k[SE];

  {
    const uint4* yg = (const uint4*)(yp + sbase) + (tid << 2);
#pragma unroll
    for (int q = 0; q < 4; q++) {
      uint4 v = yg[q];
      k[4 * q + 0] = f2s_u(v.x); k[4 * q + 1] = f2s_u(v.y);
      k[4 * q + 2] = f2s_u(v.z); k[4 * q + 3] = f2s_u(v.w);
    }
  }
  radix18(k, S, WG, tid);

  float ys[SE];
#pragma unroll
  for (int q = 0; q < 4; q++) {
    uint32_t wb = ((uint32_t)tid << 4) + ((uint32_t)q << 2);
    uint4 v = *(const uint4*)(S + (wb ^ ((wb >> 3) & 0x1Cu)));
    ys[4 * q + 0] = s2f(v.x); ys[4 * q + 1] = s2f(v.y);
    ys[4 * q + 2] = s2f(v.z); ys[4 * q + 3] = s2f(v.w);
  }

  float xs[SE];
  {
    const uint4* xg = (const uint4*)(xp + sbase) + (tid << 2);
#pragma unroll
    for (int q = 0; q < 4; q++) {
      uint4 v = xg[q];
      xs[4 * q + 0] = __uint_as_float(v.x);
      xs[4 * q + 1] = __uint_as_float(v.y);
      xs[4 * q + 2] = __uint_as_float(v.z);
      xs[4 * q + 3] = __uint_as_float(v.w);
      uint32_t g = ((uint32_t)tid << 4) + (uint32_t)(q << 2);
      k[4 * q + 0] = (f2s_u(v.x) & 0xFFFFC000u) | (g + 0);
      k[4 * q + 1] = (f2s_u(v.y) & 0xFFFFC000u) | (g + 1);
      k[4 * q + 2] = (f2s_u(v.z) & 0xFFFFC000u) | (g + 2);
      k[4 * q + 3] = (f2s_u(v.w) & 0xFFFFC000u) | (g + 3);
    }
  }
  radix18(k, S, WG, tid);

#pragma unroll
  for (int q = 0; q < 4; q++) {
    uint32_t wb = ((uint32_t)tid << 4) + ((uint32_t)q << 2);
    uint4 v = *(const uint4*)(S + (wb ^ ((wb >> 3) & 0x1Cu)));
    k[4 * q + 0] = v.x & 0x3FFFu; k[4 * q + 1] = v.y & 0x3FFFu;
    k[4 * q + 2] = v.z & 0x3FFFu; k[4 * q + 3] = v.w & 0x3FFFu;
  }
  __syncthreads();

#pragma unroll
  for (int e = 0; e < SE; e++) {
    S[swz(k[e])] = __float_as_uint(ys[e]);
  }
  __syncthreads();

  float4* og = (float4*)(yp + sbase) + (tid << 2);
#pragma unroll
  for (int q = 0; q < 4; q++) {
    uint32_t wb = ((uint32_t)tid << 4) + ((uint32_t)q << 2);
    uint4 v = *(const uint4*)(S + (wb ^ ((wb >> 3) & 0x1Cu)));
    float4 o;
    o.x = __uint_as_float(v.x) - xs[4 * q + 0];
    o.y = __uint_as_float(v.y) - xs[4 * q + 1];
    o.z = __uint_as_float(v.z) - xs[4 * q + 2];
    o.w = __uint_as_float(v.w) - xs[4 * q + 3];
    og[q] = o;
  }
}

// ---------- kernel 4: MFMA combine ----------
// B-fragments from thbT [d][p] -> single contiguous short8 per (t,kf).
__global__ __launch_bounds__(256) void combine_mfma(
    const float* __restrict__ x, const float* __restrict__ diff,
    const ushort* __restrict__ thbT, float* __restrict__ out) {
  const int tid  = threadIdx.x;
  const int lane = tid & 63;
  const int quad = lane >> 4;
  const int mloc = lane & 15;
  const int wave = tid >> 6;

  const int m0 = blockIdx.x * 64 + wave * 16;   // wave's first global row
  const int b  = m0 >> 14;
  const int n0 = m0 & (NN - 1);

  const float* dbase = diff + ((long)b * NP) * NN + n0 + mloc;
  short8 a[4];
#pragma unroll
  for (int kf = 0; kf < 4; kf++) {
#pragma unroll
    for (int j = 0; j < 8; j++) {
      const int p = kf * 32 + quad * 8 + j;
      const float v = (p < NP) ? dbase[(long)p * NN] : 0.0f;
      a[kf][j] = bf16c(v);
    }
  }

  const float inv = 1.0f / (float)NP;
  const f32x4 zero = {0.f, 0.f, 0.f, 0.f};
#pragma unroll
  for (int t = 0; t < 4; t++) {
    const int d = t * 16 + mloc;
    f32x4 acc = zero;
#pragma unroll
    for (int kf = 0; kf < 4; kf++) {
      const short8 bf = *(const short8*)(thbT + (long)d * NPP + kf * 32 + quad * 8);
      acc = __builtin_amdgcn_mfma_f32_16x16x32_bf16(a[kf], bf, acc, 0, 0, 0);
    }
#pragma unroll
    for (int r = 0; r < 4; r++) {
      const long off = (long)(m0 + quad * 4 + r) * ND + d;
      out[off] = x[off] + acc[r] * inv;
    }
  }
}

extern "C" void kernel_launch(void* const* d_in, const int* in_sizes, int n_in,
                              void* d_out, int out_size, void* d_ws, size_t ws_size,
                              hipStream_t stream) {
  const float* x     = (const float*)d_in[0];
  const float* y     = (const float*)d_in[1];
  const float* theta = (const float*)d_in[2];
  float* out = (float*)d_out;

  // workspace: [thb 16KB][thbT 16KB][xp 52.4MB][yp/diff 52.4MB]
  ushort* thb  = (ushort*)d_ws;
  ushort* thbT = thb + (size_t)NPP * ND;
  float* xp = (float*)((char*)d_ws + (1 << 15));
  float* yp = xp + (size_t)NB * NP * NN;

  normalize_theta<<<dim3(NPP), dim3(ND), 0, stream>>>(theta, thb, thbT);
  project_mfma<<<dim3((NB * NN) / 64), dim3(256), 0, stream>>>(x, y, thb, xp, yp);
  sort_diff_kernel<<<dim3(NB * NP), dim3(ST), 0, stream>>>(xp, yp);
  combine_mfma<<<dim3((NB * NN) / 64), dim3(256), 0, stream>>>(x, yp, thbT, out);
}

// Round 9
// 349.526 us; speedup vs baseline: 1.0176x; 1.0176x over previous
//
#include <hip/hip_runtime.h>
#include <cstdint>

// Problem constants (fixed by the reference): B=8, N=16384, D=64, P=100.
#define NB    8
#define NN    16384
#define ND    64
#define NP    100
#define NPP   128          // theta rows padded (zeros) for MFMA K/N tiling
#define ST    1024         // sort threads per block (16 waves)
#define SE    16           // elements per sort thread (16384/1024)
#define TROW  72           // padded LDS row stride (ushorts) for project tiles
#define DROW  68           // padded LDS row stride (ushorts) for combine diff tile

typedef __attribute__((ext_vector_type(8))) short short8;   // 8 bf16 (4 VGPRs)
typedef __attribute__((ext_vector_type(4))) float f32x4;    // MFMA C/D

// ---------- bf16 convert (RNE) ----------
__device__ __forceinline__ short bf16c(float f) {
  uint32_t u = __float_as_uint(f);
  u = u + 0x7FFFu + ((u >> 16) & 1u);
  return (short)(u >> 16);
}
__device__ __forceinline__ uint32_t bf16pk(float a, float b) {
  return (uint32_t)(ushort)bf16c(a) | ((uint32_t)(ushort)bf16c(b) << 16);
}

// ---------- sortable-key transforms ----------
__device__ __forceinline__ uint32_t f2s_u(uint32_t s) {
  return s ^ (((uint32_t)((int32_t)s >> 31)) | 0x80000000u);
}
__device__ __forceinline__ float s2f(uint32_t u) {
  uint32_t m = (u & 0x80000000u) ? 0x80000000u : 0xFFFFFFFFu;
  return __uint_as_float(u ^ m);
}

// LDS bank swizzle on word index (16B-contiguity-preserving)
__device__ __forceinline__ uint32_t swz(uint32_t w) {
  return w ^ ((w >> 3) & 0x1Cu);
}

// One LSD radix pass on 3-bit digit at shift sh, stable, in-place in S[16384].
// 16 waves: per-wave packed scan + single-wave 64-entry block scan in WG.
// NOTE (measured r3): single-wave scan + barrier BEATS redundant all-wave
// shuffle scan (+9%) -- __shfl -> ds_bpermute rides the LDS pipe on CDNA.
// NOTE (measured r8): (ST,8)/VGPR=32 with spills BEATS (ST,4)/VGPR=52
// without spills (195.6 vs 220.7 us): 2-block residency hides the spill
// traffic; 1-block residency cannot hide LDS+VMEM latency. Occupancy wins.
__device__ __forceinline__ void radix_pass(uint32_t (&k)[SE], uint32_t* S,
                                           uint32_t* WG, int tid, int sh,
                                           bool first) {
  const int lane = tid & 63;
  const int wave = tid >> 6;

  if (!first) {
#pragma unroll
    for (int q = 0; q < 4; q++) {
      uint32_t wb = ((uint32_t)tid << 4) + ((uint32_t)q << 2);
      uint4 v = *(const uint4*)(S + (wb ^ ((wb >> 3) & 0x1Cu)));
      k[4 * q + 0] = v.x; k[4 * q + 1] = v.y;
      k[4 * q + 2] = v.z; k[4 * q + 3] = v.w;
    }
  }

  // per-thread digit histogram packed 8 x 8-bit (counts <= 16)
  uint64_t c = 0;
#pragma unroll
  for (int e = 0; e < SE; e++) {
    uint32_t d = (k[e] >> sh) & 7u;
    c += 1ull << (d << 3);
  }

  uint32_t lo = (uint32_t)c, hi = (uint32_t)(c >> 32);
  uint32_t h[4];
  h[0] = (lo & 0xFFu) | ((lo & 0xFF00u) << 8);
  h[1] = ((lo >> 16) & 0xFFu) | ((lo >> 24) << 16);
  h[2] = (hi & 0xFFu) | ((hi & 0xFF00u) << 8);
  h[3] = ((hi >> 16) & 0xFFu) | ((hi >> 24) << 16);

  // wave-level inclusive scan of packed (2x16-bit) counts
#pragma unroll
  for (int off = 1; off <= 32; off <<= 1) {
#pragma unroll
    for (int i = 0; i < 4; i++) {
      uint32_t t = __shfl_up(h[i], (unsigned)off, 64);
      if (lane >= off) h[i] += t;
    }
  }

  if (lane == 63) {
#pragma unroll
    for (int i = 0; i < 4; i++) WG[(wave << 2) + i] = h[i];
  }
  __syncthreads();

  // block scan across 16 waves x 4 packed words (64 entries, one wave)
  if (tid < 64) {
    uint32_t v = WG[tid];
    uint32_t own = v;
#pragma unroll
    for (int off = 4; off <= 32; off <<= 1) {
      uint32_t t = __shfl_up(v, (unsigned)off, 64);
      if (tid >= off) v += t;
    }
    uint32_t wexcl = v - own;                       // excl across waves, same word
    uint32_t grand = __shfl(v, 60 + (tid & 3), 64); // wave-15 inclusive = totals
    uint32_t gl = grand & 0xFFFFu, gh = grand >> 16;
    uint32_t ps = gl + gh, pincl = ps;
#pragma unroll
    for (int off = 1; off <= 2; off <<= 1) {
      uint32_t t = __shfl_up(pincl, (unsigned)off, 64);
      if ((tid & 3) >= off) pincl += t;
    }
    uint32_t pexcl = pincl - ps;                    // digit base for this word pair
    uint32_t g0 = pexcl + (wexcl & 0xFFFFu);
    uint32_t g1 = pexcl + gl + (wexcl >> 16);
    WG[tid] = g0 | (g1 << 16);
  }
  __syncthreads();

  // exclusive within-thread base: WG + (inclusive h - own pre-scan counts),
  // pre-scan words recomputed from lo/hi (fewer live VGPRs across the scan)
  uint32_t p0 = WG[(wave << 2) + 0] + h[0] - ((lo & 0xFFu) | ((lo & 0xFF00u) << 8));
  uint32_t p1 = WG[(wave << 2) + 1] + h[1] - (((lo >> 16) & 0xFFu) | ((lo >> 24) << 16));
  uint32_t p2 = WG[(wave << 2) + 2] + h[2] - ((hi & 0xFFu) | ((hi & 0xFF00u) << 8));
  uint32_t p3 = WG[(wave << 2) + 3] + h[3] - (((hi >> 16) & 0xFFu) | ((hi >> 24) << 16));
  uint64_t pc0 = (uint64_t)p0 | ((uint64_t)p1 << 32);
  uint64_t pc1 = (uint64_t)p2 | ((uint64_t)p3 << 32);

#pragma unroll
  for (int e = 0; e < SE; e++) {
    uint32_t d = (k[e] >> sh) & 7u;
    uint32_t s16 = (d & 3u) << 4;
    bool lo4 = d < 4u;
    uint64_t t = lo4 ? pc0 : pc1;
    uint32_t pos = (uint32_t)(t >> s16) & 0xFFFFu;
    uint64_t inc = 1ull << s16;
    pc0 += lo4 ? inc : 0ull;
    pc1 += lo4 ? 0ull : inc;
    S[swz(pos)] = k[e];
  }
  __syncthreads();
}

__device__ __forceinline__ void radix18(uint32_t (&k)[SE], uint32_t* S,
                                        uint32_t* WG, int tid) {
  bool first = true;
  for (int sh = 14; sh < 32; sh += 3) {
    radix_pass(k, S, WG, tid, sh, first);
    first = false;
  }
}

// ---------- kernel 1: normalize theta -> bf16 thb [p][d] AND thbT [d][p] ----
__global__ void normalize_theta(const float* __restrict__ theta,
                                ushort* __restrict__ thb,
                                ushort* __restrict__ thbT) {
  const int p = blockIdx.x, t = threadIdx.x;
  ushort v16 = 0;
  if (p < NP) {
    float v = theta[p * ND + t];
    float ss = v * v;
#pragma unroll
    for (int off = 32; off >= 1; off >>= 1) ss += __shfl_xor(ss, off, 64);
    v16 = (ushort)bf16c(v * rsqrtf(ss));
  }
  thb[p * ND + t] = v16;
  thbT[t * NPP + p] = v16;
}

// ---------- kernel 2: MFMA projection (x AND y per block, LDS-staged) ------
// Stage the block's 64x64 fp32 tiles of x and y into LDS as bf16 via fully
// coalesced global loads (1KB/instr), then read MFMA A-fragments with
// ds_read_b128 (72-ushort padded rows -> 2-way bank aliasing = free).
__global__ __launch_bounds__(256) void project_mfma(
    const float* __restrict__ x, const float* __restrict__ y,
    const ushort* __restrict__ thb, float* __restrict__ xp,
    float* __restrict__ yp) {
  __shared__ ushort XT[64 * TROW];
  __shared__ ushort YT[64 * TROW];
  const int tid  = threadIdx.x;
  const int lane = tid & 63;
  const int quad = lane >> 4;
  const int mloc = lane & 15;
  const int wave = tid >> 6;

  const int m0 = blockIdx.x * 64 + wave * 16;   // 2048 blocks, 64 rows each
  const int b  = m0 >> 14;
  const int n0 = m0 & (NN - 1);

  // --- stage: 64 rows x 64 cols, 1024 float4 per matrix, 4 per thread ---
  {
    const float4* gx = (const float4*)(x + (long)blockIdx.x * 64 * ND);
    const float4* gy = (const float4*)(y + (long)blockIdx.x * 64 * ND);
#pragma unroll
    for (int i = 0; i < 4; i++) {
      const int f4 = tid + 256 * i;        // 0..1023
      const int row = f4 >> 4;             // 16 float4 per row
      const int c4  = f4 & 15;
      float4 vx = gx[f4];
      float4 vy = gy[f4];
      uint2 px, py;
      px.x = bf16pk(vx.x, vx.y); px.y = bf16pk(vx.z, vx.w);
      py.x = bf16pk(vy.x, vy.y); py.y = bf16pk(vy.z, vy.w);
      const int us = row * TROW + c4 * 4;  // ushort index, 8B-aligned
      *(uint2*)(XT + us) = px;
      *(uint2*)(YT + us) = py;
    }
  }
  __syncthreads();

  // --- fragments from LDS ---
  const int fr = wave * 16 + mloc;         // row within block tile
  const short8 ax0 = *(const short8*)(XT + fr * TROW + quad * 8);
  const short8 ax1 = *(const short8*)(XT + fr * TROW + 32 + quad * 8);
  const short8 ay0 = *(const short8*)(YT + fr * TROW + quad * 8);
  const short8 ay1 = *(const short8*)(YT + fr * TROW + 32 + quad * 8);

  const f32x4 zero = {0.f, 0.f, 0.f, 0.f};
#pragma unroll
  for (int t = 0; t < 7; t++) {
    const int p = t * 16 + mloc;
    const short8 b0 = *(const short8*)(thb + p * ND + quad * 8);
    const short8 b1 = *(const short8*)(thb + p * ND + 32 + quad * 8);
    f32x4 accx = __builtin_amdgcn_mfma_f32_16x16x32_bf16(ax0, b0, zero, 0, 0, 0);
    accx = __builtin_amdgcn_mfma_f32_16x16x32_bf16(ax1, b1, accx, 0, 0, 0);
    f32x4 accy = __builtin_amdgcn_mfma_f32_16x16x32_bf16(ay0, b0, zero, 0, 0, 0);
    accy = __builtin_amdgcn_mfma_f32_16x16x32_bf16(ay1, b1, accy, 0, 0, 0);
    if (t < 6 || mloc < (NP - 96)) {
      const long off = ((long)b * NP + p) * NN + n0 + quad * 4;
      *(f32x4*)(xp + off) = accx;   // rows quad*4+r are consecutive n -> float4
      *(f32x4*)(yp + off) = accy;
    }
  }
}

// ---------- kernel 3: per-(b,p) radix-sort y, rank x, write diff ----------
// x_proj values are kept in registers from the key-build phase; the final
// phase positions (tid<<4 + 4q+i) coincide with the key-build positions,
// so no tail re-read of xp is needed (bit-identical subtraction).
__global__ __launch_bounds__(ST, 8) void sort_diff_kernel(
    const float* __restrict__ xp, float* __restrict__ yp) {
  __shared__ uint32_t S[NN];    // 64 KB
  __shared__ uint32_t WG[64];
  const int tid = threadIdx.x;
  const long sbase = (long)blockIdx.x * NN;
  uint32_t k[SE];

  {
    const uint4* yg = (const uint4*)(yp + sbase) + (tid << 2);
#pragma unroll
    for (int q = 0; q < 4; q++) {
      uint4 v = yg[q];
      k[4 * q + 0] = f2s_u(v.x); k[4 * q + 1] = f2s_u(v.y);
      k[4 * q + 2] = f2s_u(v.z); k[4 * q + 3] = f2s_u(v.w);
    }
  }
  radix18(k, S, WG, tid);

  float ys[SE];
#pragma unroll
  for (int q = 0; q < 4; q++) {
    uint32_t wb = ((uint32_t)tid << 4) + ((uint32_t)q << 2);
    uint4 v = *(const uint4*)(S + (wb ^ ((wb >> 3) & 0x1Cu)));
    ys[4 * q + 0] = s2f(v.x); ys[4 * q + 1] = s2f(v.y);
    ys[4 * q + 2] = s2f(v.z); ys[4 * q + 3] = s2f(v.w);
  }

  float xs[SE];
  {
    const uint4* xg = (const uint4*)(xp + sbase) + (tid << 2);
#pragma unroll
    for (int q = 0; q < 4; q++) {
      uint4 v = xg[q];
      xs[4 * q + 0] = __uint_as_float(v.x);
      xs[4 * q + 1] = __uint_as_float(v.y);
      xs[4 * q + 2] = __uint_as_float(v.z);
      xs[4 * q + 3] = __uint_as_float(v.w);
      uint32_t g = ((uint32_t)tid << 4) + (uint32_t)(q << 2);
      k[4 * q + 0] = (f2s_u(v.x) & 0xFFFFC000u) | (g + 0);
      k[4 * q + 1] = (f2s_u(v.y) & 0xFFFFC000u) | (g + 1);
      k[4 * q + 2] = (f2s_u(v.z) & 0xFFFFC000u) | (g + 2);
      k[4 * q + 3] = (f2s_u(v.w) & 0xFFFFC000u) | (g + 3);
    }
  }
  radix18(k, S, WG, tid);

#pragma unroll
  for (int q = 0; q < 4; q++) {
    uint32_t wb = ((uint32_t)tid << 4) + ((uint32_t)q << 2);
    uint4 v = *(const uint4*)(S + (wb ^ ((wb >> 3) & 0x1Cu)));
    k[4 * q + 0] = v.x & 0x3FFFu; k[4 * q + 1] = v.y & 0x3FFFu;
    k[4 * q + 2] = v.z & 0x3FFFu; k[4 * q + 3] = v.w & 0x3FFFu;
  }
  __syncthreads();

#pragma unroll
  for (int e = 0; e < SE; e++) {
    S[swz(k[e])] = __float_as_uint(ys[e]);
  }
  __syncthreads();

  float4* og = (float4*)(yp + sbase) + (tid << 2);
#pragma unroll
  for (int q = 0; q < 4; q++) {
    uint32_t wb = ((uint32_t)tid << 4) + ((uint32_t)q << 2);
    uint4 v = *(const uint4*)(S + (wb ^ ((wb >> 3) & 0x1Cu)));
    float4 o;
    o.x = __uint_as_float(v.x) - xs[4 * q + 0];
    o.y = __uint_as_float(v.y) - xs[4 * q + 1];
    o.z = __uint_as_float(v.z) - xs[4 * q + 2];
    o.w = __uint_as_float(v.w) - xs[4 * q + 3];
    og[q] = o;
  }
}

// ---------- kernel 4: MFMA combine (LDS-staged diff tile) ----------
// The block's diff tile [100][64] is staged via COALESCED float4 loads
// (7 instrs/thread replace 32 strided scalar loads), packed bf16 into
// DT[p][DROW].  A-frags then come from LDS (ds_read_u16).  Same bf16c
// values, same MFMA order -> bit-identical output.
__global__ __launch_bounds__(256) void combine_mfma(
    const float* __restrict__ x, const float* __restrict__ diff,
    const ushort* __restrict__ thbT, float* __restrict__ out) {
  __shared__ ushort DT[104 * DROW];   // 100 rows used + 4 pad rows (masked)
  const int tid  = threadIdx.x;
  const int lane = tid & 63;
  const int quad = lane >> 4;
  const int mloc = lane & 15;
  const int wave = tid >> 6;

  const int mb = blockIdx.x * 64;               // block's first global row
  const int b  = mb >> 14;
  const int nb0 = mb & (NN - 1);                // block-uniform n base

  // --- stage diff[b][0..100][nb0..nb0+64) as bf16 into DT ---
  {
    const float* dsrc = diff + (long)b * NP * NN + nb0;
#pragma unroll
    for (int it = 0; it < 7; it++) {
      const int f = tid + 256 * it;             // 0..1791
      if (f < NP * 16) {
        const int p  = f >> 4;                  // 16 float4 per p-row
        const int c4 = f & 15;
        float4 v = *(const float4*)(dsrc + (long)p * NN + c4 * 4);
        uint2 pk;
        pk.x = bf16pk(v.x, v.y);
        pk.y = bf16pk(v.z, v.w);
        *(uint2*)(DT + p * DROW + c4 * 4) = pk; // 136B rows -> 8B aligned
      }
    }
  }
  __syncthreads();

  // --- A fragments from LDS: a[kf][j] = DT[kf*32+quad*8+j][wave*16+mloc] ---
  const int nl = wave * 16 + mloc;
  short8 a[4];
#pragma unroll
  for (int kf = 0; kf < 4; kf++) {
#pragma unroll
    for (int j = 0; j < 8; j++) {
      a[kf][j] = (short)DT[(kf * 32 + quad * 8 + j) * DROW + nl];
    }
  }
  // K-padding mask: p = 96 + quad*8 + j must be < NP for kf=3
  {
    const int pb = 96 + quad * 8;
#pragma unroll
    for (int j = 0; j < 8; j++) {
      if (pb + j >= NP) a[3][j] = 0;
    }
  }

  const int m0 = mb + wave * 16;                // wave's first global row
  const float inv = 1.0f / (float)NP;
  const f32x4 zero = {0.f, 0.f, 0.f, 0.f};
#pragma unroll
  for (int t = 0; t < 4; t++) {
    const int d = t * 16 + mloc;
    f32x4 acc = zero;
#pragma unroll
    for (int kf = 0; kf < 4; kf++) {
      const short8 bf = *(const short8*)(thbT + (long)d * NPP + kf * 32 + quad * 8);
      acc = __builtin_amdgcn_mfma_f32_16x16x32_bf16(a[kf], bf, acc, 0, 0, 0);
    }
#pragma unroll
    for (int r = 0; r < 4; r++) {
      const long off = (long)(m0 + quad * 4 + r) * ND + d;
      out[off] = x[off] + acc[r] * inv;
    }
  }
}

extern "C" void kernel_launch(void* const* d_in, const int* in_sizes, int n_in,
                              void* d_out, int out_size, void* d_ws, size_t ws_size,
                              hipStream_t stream) {
  const float* x     = (const float*)d_in[0];
  const float* y     = (const float*)d_in[1];
  const float* theta = (const float*)d_in[2];
  float* out = (float*)d_out;

  // workspace: [thb 16KB][thbT 16KB][xp 52.4MB][yp/diff 52.4MB]
  ushort* thb  = (ushort*)d_ws;
  ushort* thbT = thb + (size_t)NPP * ND;
  float* xp = (float*)((char*)d_ws + (1 << 15));
  float* yp = xp + (size_t)NB * NP * NN;

  normalize_theta<<<dim3(NPP), dim3(ND), 0, stream>>>(theta, thb, thbT);
  project_mfma<<<dim3((NB * NN) / 64), dim3(256), 0, stream>>>(x, y, thb, xp, yp);
  sort_diff_kernel<<<dim3(NB * NP), dim3(ST), 0, stream>>>(xp, yp);
  combine_mfma<<<dim3((NB * NN) / 64), dim3(256), 0, stream>>>(x, yp, thbT, out);
}

// Round 10
// 337.794 us; speedup vs baseline: 1.0530x; 1.0347x over previous
//
#include <hip/hip_runtime.h>
#include <cstdint>

// Problem constants (fixed by the reference): B=8, N=16384, D=64, P=100.
#define NB    8
#define NN    16384
#define ND    64
#define NP    100
#define NPP   128          // theta rows padded (zeros) for MFMA K/N tiling
#define ST    1024         // sort threads per block (16 waves)
#define SE    16           // elements per sort thread (16384/1024)
#define TROW  72           // padded LDS row stride (ushorts) for project tiles

typedef __attribute__((ext_vector_type(8))) short short8;   // 8 bf16 (4 VGPRs)
typedef __attribute__((ext_vector_type(4))) float f32x4;    // MFMA C/D

// ---------- bf16 convert (RNE) ----------
__device__ __forceinline__ short bf16c(float f) {
  uint32_t u = __float_as_uint(f);
  u = u + 0x7FFFu + ((u >> 16) & 1u);
  return (short)(u >> 16);
}
__device__ __forceinline__ uint32_t bf16pk(float a, float b) {
  return (uint32_t)(ushort)bf16c(a) | ((uint32_t)(ushort)bf16c(b) << 16);
}

// ---------- sortable-key transforms ----------
__device__ __forceinline__ uint32_t f2s_u(uint32_t s) {
  return s ^ (((uint32_t)((int32_t)s >> 31)) | 0x80000000u);
}
__device__ __forceinline__ float s2f(uint32_t u) {
  uint32_t m = (u & 0x80000000u) ? 0x80000000u : 0xFFFFFFFFu;
  return __uint_as_float(u ^ m);
}

// LDS bank swizzle on word index (16B-contiguity-preserving)
__device__ __forceinline__ uint32_t swz(uint32_t w) {
  return w ^ ((w >> 3) & 0x1Cu);
}

// One LSD radix pass on 3-bit digit at shift sh, stable, in-place in S[16384].
// 16 waves: per-wave packed scan + single-wave 64-entry block scan in WG.
// NOTE (measured r3): single-wave scan + barrier BEATS redundant all-wave
// shuffle scan (+9%) -- __shfl -> ds_bpermute rides the LDS pipe on CDNA.
// NOTE (measured r8): (ST,8)/VGPR=32 with spills BEATS (ST,4)/VGPR=52
// without spills (195.6 vs 220.7 us): 2-block residency hides the spill
// traffic; 1-block residency cannot hide LDS+VMEM latency. Occupancy wins.
__device__ __forceinline__ void radix_pass(uint32_t (&k)[SE], uint32_t* S,
                                           uint32_t* WG, int tid, int sh,
                                           bool first) {
  const int lane = tid & 63;
  const int wave = tid >> 6;

  if (!first) {
#pragma unroll
    for (int q = 0; q < 4; q++) {
      uint32_t wb = ((uint32_t)tid << 4) + ((uint32_t)q << 2);
      uint4 v = *(const uint4*)(S + (wb ^ ((wb >> 3) & 0x1Cu)));
      k[4 * q + 0] = v.x; k[4 * q + 1] = v.y;
      k[4 * q + 2] = v.z; k[4 * q + 3] = v.w;
    }
  }

  // per-thread digit histogram packed 8 x 8-bit (counts <= 16)
  uint64_t c = 0;
#pragma unroll
  for (int e = 0; e < SE; e++) {
    uint32_t d = (k[e] >> sh) & 7u;
    c += 1ull << (d << 3);
  }

  uint32_t lo = (uint32_t)c, hi = (uint32_t)(c >> 32);
  uint32_t h[4];
  h[0] = (lo & 0xFFu) | ((lo & 0xFF00u) << 8);
  h[1] = ((lo >> 16) & 0xFFu) | ((lo >> 24) << 16);
  h[2] = (hi & 0xFFu) | ((hi & 0xFF00u) << 8);
  h[3] = ((hi >> 16) & 0xFFu) | ((hi >> 24) << 16);

  // wave-level inclusive scan of packed (2x16-bit) counts
#pragma unroll
  for (int off = 1; off <= 32; off <<= 1) {
#pragma unroll
    for (int i = 0; i < 4; i++) {
      uint32_t t = __shfl_up(h[i], (unsigned)off, 64);
      if (lane >= off) h[i] += t;
    }
  }

  if (lane == 63) {
#pragma unroll
    for (int i = 0; i < 4; i++) WG[(wave << 2) + i] = h[i];
  }
  __syncthreads();

  // block scan across 16 waves x 4 packed words (64 entries, one wave)
  if (tid < 64) {
    uint32_t v = WG[tid];
    uint32_t own = v;
#pragma unroll
    for (int off = 4; off <= 32; off <<= 1) {
      uint32_t t = __shfl_up(v, (unsigned)off, 64);
      if (tid >= off) v += t;
    }
    uint32_t wexcl = v - own;                       // excl across waves, same word
    uint32_t grand = __shfl(v, 60 + (tid & 3), 64); // wave-15 inclusive = totals
    uint32_t gl = grand & 0xFFFFu, gh = grand >> 16;
    uint32_t ps = gl + gh, pincl = ps;
#pragma unroll
    for (int off = 1; off <= 2; off <<= 1) {
      uint32_t t = __shfl_up(pincl, (unsigned)off, 64);
      if ((tid & 3) >= off) pincl += t;
    }
    uint32_t pexcl = pincl - ps;                    // digit base for this word pair
    uint32_t g0 = pexcl + (wexcl & 0xFFFFu);
    uint32_t g1 = pexcl + gl + (wexcl >> 16);
    WG[tid] = g0 | (g1 << 16);
  }
  __syncthreads();

  // exclusive within-thread base: WG + (inclusive h - own pre-scan counts),
  // pre-scan words recomputed from lo/hi (fewer live VGPRs across the scan)
  uint32_t p0 = WG[(wave << 2) + 0] + h[0] - ((lo & 0xFFu) | ((lo & 0xFF00u) << 8));
  uint32_t p1 = WG[(wave << 2) + 1] + h[1] - (((lo >> 16) & 0xFFu) | ((lo >> 24) << 16));
  uint32_t p2 = WG[(wave << 2) + 2] + h[2] - ((hi & 0xFFu) | ((hi & 0xFF00u) << 8));
  uint32_t p3 = WG[(wave << 2) + 3] + h[3] - (((hi >> 16) & 0xFFu) | ((hi >> 24) << 16));
  uint64_t pc0 = (uint64_t)p0 | ((uint64_t)p1 << 32);
  uint64_t pc1 = (uint64_t)p2 | ((uint64_t)p3 << 32);

#pragma unroll
  for (int e = 0; e < SE; e++) {
    uint32_t d = (k[e] >> sh) & 7u;
    uint32_t s16 = (d & 3u) << 4;
    bool lo4 = d < 4u;
    uint64_t t = lo4 ? pc0 : pc1;
    uint32_t pos = (uint32_t)(t >> s16) & 0xFFFFu;
    uint64_t inc = 1ull << s16;
    pc0 += lo4 ? inc : 0ull;
    pc1 += lo4 ? 0ull : inc;
    S[swz(pos)] = k[e];
  }
  __syncthreads();
}

__device__ __forceinline__ void radix18(uint32_t (&k)[SE], uint32_t* S,
                                        uint32_t* WG, int tid) {
  bool first = true;
  for (int sh = 14; sh < 32; sh += 3) {
    radix_pass(k, S, WG, tid, sh, first);
    first = false;
  }
}

// ---------- kernel 1: normalize theta -> bf16 thb [p][d] AND thbT [d][p] ----
__global__ void normalize_theta(const float* __restrict__ theta,
                                ushort* __restrict__ thb,
                                ushort* __restrict__ thbT) {
  const int p = blockIdx.x, t = threadIdx.x;
  ushort v16 = 0;
  if (p < NP) {
    float v = theta[p * ND + t];
    float ss = v * v;
#pragma unroll
    for (int off = 32; off >= 1; off >>= 1) ss += __shfl_xor(ss, off, 64);
    v16 = (ushort)bf16c(v * rsqrtf(ss));
  }
  thb[p * ND + t] = v16;
  thbT[t * NPP + p] = v16;
}

// ---------- kernel 2: MFMA projection (x AND y per block, LDS-staged) ------
// Stage the block's 64x64 fp32 tiles of x and y into LDS as bf16 via fully
// coalesced global loads (1KB/instr), then read MFMA A-fragments with
// ds_read_b128 (72-ushort padded rows -> 2-way bank aliasing = free).
__global__ __launch_bounds__(256) void project_mfma(
    const float* __restrict__ x, const float* __restrict__ y,
    const ushort* __restrict__ thb, float* __restrict__ xp,
    float* __restrict__ yp) {
  __shared__ ushort XT[64 * TROW];
  __shared__ ushort YT[64 * TROW];
  const int tid  = threadIdx.x;
  const int lane = tid & 63;
  const int quad = lane >> 4;
  const int mloc = lane & 15;
  const int wave = tid >> 6;

  const int m0 = blockIdx.x * 64 + wave * 16;   // 2048 blocks, 64 rows each
  const int b  = m0 >> 14;
  const int n0 = m0 & (NN - 1);

  // --- stage: 64 rows x 64 cols, 1024 float4 per matrix, 4 per thread ---
  {
    const float4* gx = (const float4*)(x + (long)blockIdx.x * 64 * ND);
    const float4* gy = (const float4*)(y + (long)blockIdx.x * 64 * ND);
#pragma unroll
    for (int i = 0; i < 4; i++) {
      const int f4 = tid + 256 * i;        // 0..1023
      const int row = f4 >> 4;             // 16 float4 per row
      const int c4  = f4 & 15;
      float4 vx = gx[f4];
      float4 vy = gy[f4];
      uint2 px, py;
      px.x = bf16pk(vx.x, vx.y); px.y = bf16pk(vx.z, vx.w);
      py.x = bf16pk(vy.x, vy.y); py.y = bf16pk(vy.z, vy.w);
      const int us = row * TROW + c4 * 4;  // ushort index, 8B-aligned
      *(uint2*)(XT + us) = px;
      *(uint2*)(YT + us) = py;
    }
  }
  __syncthreads();

  // --- fragments from LDS ---
  const int fr = wave * 16 + mloc;         // row within block tile
  const short8 ax0 = *(const short8*)(XT + fr * TROW + quad * 8);
  const short8 ax1 = *(const short8*)(XT + fr * TROW + 32 + quad * 8);
  const short8 ay0 = *(const short8*)(YT + fr * TROW + quad * 8);
  const short8 ay1 = *(const short8*)(YT + fr * TROW + 32 + quad * 8);

  const f32x4 zero = {0.f, 0.f, 0.f, 0.f};
#pragma unroll
  for (int t = 0; t < 7; t++) {
    const int p = t * 16 + mloc;
    const short8 b0 = *(const short8*)(thb + p * ND + quad * 8);
    const short8 b1 = *(const short8*)(thb + p * ND + 32 + quad * 8);
    f32x4 accx = __builtin_amdgcn_mfma_f32_16x16x32_bf16(ax0, b0, zero, 0, 0, 0);
    accx = __builtin_amdgcn_mfma_f32_16x16x32_bf16(ax1, b1, accx, 0, 0, 0);
    f32x4 accy = __builtin_amdgcn_mfma_f32_16x16x32_bf16(ay0, b0, zero, 0, 0, 0);
    accy = __builtin_amdgcn_mfma_f32_16x16x32_bf16(ay1, b1, accy, 0, 0, 0);
    if (t < 6 || mloc < (NP - 96)) {
      const long off = ((long)b * NP + p) * NN + n0 + quad * 4;
      *(f32x4*)(xp + off) = accx;   // rows quad*4+r are consecutive n -> float4
      *(f32x4*)(yp + off) = accy;
    }
  }
}

// ---------- kernel 3: per-(b,p) radix-sort y, rank x, write diff ----------
// x_proj values are kept in registers from the key-build phase; the final
// phase positions (tid<<4 + 4q+i) coincide with the key-build positions,
// so no tail re-read of xp is needed (bit-identical subtraction).
__global__ __launch_bounds__(ST, 8) void sort_diff_kernel(
    const float* __restrict__ xp, float* __restrict__ yp) {
  __shared__ uint32_t S[NN];    // 64 KB
  __shared__ uint32_t WG[64];
  const int tid = threadIdx.x;
  const long sbase = (long)blockIdx.x * NN;
  uint32_t k[SE];

  {
    const uint4* yg = (const uint4*)(yp + sbase) + (tid << 2);
#pragma unroll
    for (int q = 0; q < 4; q++) {
      uint4 v = yg[q];
      k[4 * q + 0] = f2s_u(v.x); k[4 * q + 1] = f2s_u(v.y);
      k[4 * q + 2] = f2s_u(v.z); k[4 * q + 3] = f2s_u(v.w);
    }
  }
  radix18(k, S, WG, tid);

  float ys[SE];
#pragma unroll
  for (int q = 0; q < 4; q++) {
    uint32_t wb = ((uint32_t)tid << 4) + ((uint32_t)q << 2);
    uint4 v = *(const uint4*)(S + (wb ^ ((wb >> 3) & 0x1Cu)));
    ys[4 * q + 0] = s2f(v.x); ys[4 * q + 1] = s2f(v.y);
    ys[4 * q + 2] = s2f(v.z); ys[4 * q + 3] = s2f(v.w);
  }

  float xs[SE];
  {
    const uint4* xg = (const uint4*)(xp + sbase) + (tid << 2);
#pragma unroll
    for (int q = 0; q < 4; q++) {
      uint4 v = xg[q];
      xs[4 * q + 0] = __uint_as_float(v.x);
      xs[4 * q + 1] = __uint_as_float(v.y);
      xs[4 * q + 2] = __uint_as_float(v.z);
      xs[4 * q + 3] = __uint_as_float(v.w);
      uint32_t g = ((uint32_t)tid << 4) + (uint32_t)(q << 2);
      k[4 * q + 0] = (f2s_u(v.x) & 0xFFFFC000u) | (g + 0);
      k[4 * q + 1] = (f2s_u(v.y) & 0xFFFFC000u) | (g + 1);
      k[4 * q + 2] = (f2s_u(v.z) & 0xFFFFC000u) | (g + 2);
      k[4 * q + 3] = (f2s_u(v.w) & 0xFFFFC000u) | (g + 3);
    }
  }
  radix18(k, S, WG, tid);

#pragma unroll
  for (int q = 0; q < 4; q++) {
    uint32_t wb = ((uint32_t)tid << 4) + ((uint32_t)q << 2);
    uint4 v = *(const uint4*)(S + (wb ^ ((wb >> 3) & 0x1Cu)));
    k[4 * q + 0] = v.x & 0x3FFFu; k[4 * q + 1] = v.y & 0x3FFFu;
    k[4 * q + 2] = v.z & 0x3FFFu; k[4 * q + 3] = v.w & 0x3FFFu;
  }
  __syncthreads();

#pragma unroll
  for (int e = 0; e < SE; e++) {
    S[swz(k[e])] = __float_as_uint(ys[e]);
  }
  __syncthreads();

  float4* og = (float4*)(yp + sbase) + (tid << 2);
#pragma unroll
  for (int q = 0; q < 4; q++) {
    uint32_t wb = ((uint32_t)tid << 4) + ((uint32_t)q << 2);
    uint4 v = *(const uint4*)(S + (wb ^ ((wb >> 3) & 0x1Cu)));
    float4 o;
    o.x = __uint_as_float(v.x) - xs[4 * q + 0];
    o.y = __uint_as_float(v.y) - xs[4 * q + 1];
    o.z = __uint_as_float(v.z) - xs[4 * q + 2];
    o.w = __uint_as_float(v.w) - xs[4 * q + 3];
    og[q] = o;
  }
}

// ---------- kernel 4: MFMA combine ----------
// A-frags: strided scalar global gather from diff (L3-resident, hidden at
// high occupancy -- measured FASTER than LDS staging, r9: +17us regression).
// B-frags: single contiguous short8 per (t,kf) from thbT [d][p].
__global__ __launch_bounds__(256) void combine_mfma(
    const float* __restrict__ x, const float* __restrict__ diff,
    const ushort* __restrict__ thbT, float* __restrict__ out) {
  const int tid  = threadIdx.x;
  const int lane = tid & 63;
  const int quad = lane >> 4;
  const int mloc = lane & 15;
  const int wave = tid >> 6;

  const int m0 = blockIdx.x * 64 + wave * 16;   // wave's first global row
  const int b  = m0 >> 14;
  const int n0 = m0 & (NN - 1);

  const float* dbase = diff + ((long)b * NP) * NN + n0 + mloc;
  short8 a[4];
#pragma unroll
  for (int kf = 0; kf < 4; kf++) {
#pragma unroll
    for (int j = 0; j < 8; j++) {
      const int p = kf * 32 + quad * 8 + j;
      const float v = (p < NP) ? dbase[(long)p * NN] : 0.0f;
      a[kf][j] = bf16c(v);
    }
  }

  const float inv = 1.0f / (float)NP;
  const f32x4 zero = {0.f, 0.f, 0.f, 0.f};
#pragma unroll
  for (int t = 0; t < 4; t++) {
    const int d = t * 16 + mloc;
    f32x4 acc = zero;
#pragma unroll
    for (int kf = 0; kf < 4; kf++) {
      const short8 bf = *(const short8*)(thbT + (long)d * NPP + kf * 32 + quad * 8);
      acc = __builtin_amdgcn_mfma_f32_16x16x32_bf16(a[kf], bf, acc, 0, 0, 0);
    }
#pragma unroll
    for (int r = 0; r < 4; r++) {
      const long off = (long)(m0 + quad * 4 + r) * ND + d;
      out[off] = x[off] + acc[r] * inv;
    }
  }
}

extern "C" void kernel_launch(void* const* d_in, const int* in_sizes, int n_in,
                              void* d_out, int out_size, void* d_ws, size_t ws_size,
                              hipStream_t stream) {
  const float* x     = (const float*)d_in[0];
  const float* y     = (const float*)d_in[1];
  const float* theta = (const float*)d_in[2];
  float* out = (float*)d_out;

  // workspace: [thb 16KB][thbT 16KB][xp 52.4MB][yp/diff 52.4MB]
  ushort* thb  = (ushort*)d_ws;
  ushort* thbT = thb + (size_t)NPP * ND;
  float* xp = (float*)((char*)d_ws + (1 << 15));
  float* yp = xp + (size_t)NB * NP * NN;

  normalize_theta<<<dim3(NPP), dim3(ND), 0, stream>>>(theta, thb, thbT);
  project_mfma<<<dim3((NB * NN) / 64), dim3(256), 0, stream>>>(x, y, thb, xp, yp);
  sort_diff_kernel<<<dim3(NB * NP), dim3(ST), 0, stream>>>(xp, yp);
  combine_mfma<<<dim3((NB * NN) / 64), dim3(256), 0, stream>>>(x, yp, thbT, out);
}

// Round 11
// 331.452 us; speedup vs baseline: 1.0731x; 1.0191x over previous
//
#include <hip/hip_runtime.h>
#include <cstdint>

// Problem constants (fixed by the reference): B=8, N=16384, D=64, P=100.
#define NB    8
#define NN    16384
#define ND    64
#define NP    100
#define NPP   128          // theta rows padded (zeros) for MFMA K/N tiling
#define ST    1024         // sort threads per block (16 waves)
#define SE    16           // elements per sort thread (16384/1024)
#define TROW  72           // padded LDS row stride (ushorts) for project tiles

typedef __attribute__((ext_vector_type(8))) short short8;   // 8 bf16 (4 VGPRs)
typedef __attribute__((ext_vector_type(4))) float f32x4;    // MFMA C/D

// ---------- bf16 convert (RNE) ----------
__device__ __forceinline__ short bf16c(float f) {
  uint32_t u = __float_as_uint(f);
  u = u + 0x7FFFu + ((u >> 16) & 1u);
  return (short)(u >> 16);
}
__device__ __forceinline__ uint32_t bf16pk(float a, float b) {
  return (uint32_t)(ushort)bf16c(a) | ((uint32_t)(ushort)bf16c(b) << 16);
}

// ---------- sortable-key transforms ----------
__device__ __forceinline__ uint32_t f2s_u(uint32_t s) {
  return s ^ (((uint32_t)((int32_t)s >> 31)) | 0x80000000u);
}
__device__ __forceinline__ float s2f(uint32_t u) {
  uint32_t m = (u & 0x80000000u) ? 0x80000000u : 0xFFFFFFFFu;
  return __uint_as_float(u ^ m);
}

// LDS bank swizzle on word index (16B-contiguity-preserving)
__device__ __forceinline__ uint32_t swz(uint32_t w) {
  return w ^ ((w >> 3) & 0x1Cu);
}

// One LSD radix pass on 3-bit digit at shift sh, stable, in-place in S[16384].
// 16 waves: per-wave packed scan + single-wave 64-entry block scan in WG.
// NOTE (measured r3): single-wave scan + barrier BEATS redundant all-wave
// shuffle scan (+9%) -- __shfl -> ds_bpermute rides the LDS pipe on CDNA.
// NOTE (measured r8): (ST,8)/VGPR=32 with spills BEATS (ST,4)/VGPR=52
// without spills (195.6 vs 220.7 us): 2-block residency hides the spill
// traffic; 1-block residency cannot hide LDS+VMEM latency. Occupancy wins.
__device__ __forceinline__ void radix_pass(uint32_t (&k)[SE], uint32_t* S,
                                           uint32_t* WG, int tid, int sh,
                                           bool first) {
  const int lane = tid & 63;
  const int wave = tid >> 6;

  if (!first) {
#pragma unroll
    for (int q = 0; q < 4; q++) {
      uint32_t wb = ((uint32_t)tid << 4) + ((uint32_t)q << 2);
      uint4 v = *(const uint4*)(S + (wb ^ ((wb >> 3) & 0x1Cu)));
      k[4 * q + 0] = v.x; k[4 * q + 1] = v.y;
      k[4 * q + 2] = v.z; k[4 * q + 3] = v.w;
    }
  }

  // per-thread digit histogram packed 8 x 8-bit (counts <= 16)
  uint64_t c = 0;
#pragma unroll
  for (int e = 0; e < SE; e++) {
    uint32_t d = (k[e] >> sh) & 7u;
    c += 1ull << (d << 3);
  }

  uint32_t lo = (uint32_t)c, hi = (uint32_t)(c >> 32);
  uint32_t h[4];
  h[0] = (lo & 0xFFu) | ((lo & 0xFF00u) << 8);
  h[1] = ((lo >> 16) & 0xFFu) | ((lo >> 24) << 16);
  h[2] = (hi & 0xFFu) | ((hi & 0xFF00u) << 8);
  h[3] = ((hi >> 16) & 0xFFu) | ((hi >> 24) << 16);

  // wave-level inclusive scan of packed (2x16-bit) counts
#pragma unroll
  for (int off = 1; off <= 32; off <<= 1) {
#pragma unroll
    for (int i = 0; i < 4; i++) {
      uint32_t t = __shfl_up(h[i], (unsigned)off, 64);
      if (lane >= off) h[i] += t;
    }
  }

  if (lane == 63) {
#pragma unroll
    for (int i = 0; i < 4; i++) WG[(wave << 2) + i] = h[i];
  }
  __syncthreads();

  // block scan across 16 waves x 4 packed words (64 entries, one wave)
  if (tid < 64) {
    uint32_t v = WG[tid];
    uint32_t own = v;
#pragma unroll
    for (int off = 4; off <= 32; off <<= 1) {
      uint32_t t = __shfl_up(v, (unsigned)off, 64);
      if (tid >= off) v += t;
    }
    uint32_t wexcl = v - own;                       // excl across waves, same word
    uint32_t grand = __shfl(v, 60 + (tid & 3), 64); // wave-15 inclusive = totals
    uint32_t gl = grand & 0xFFFFu, gh = grand >> 16;
    uint32_t ps = gl + gh, pincl = ps;
#pragma unroll
    for (int off = 1; off <= 2; off <<= 1) {
      uint32_t t = __shfl_up(pincl, (unsigned)off, 64);
      if ((tid & 3) >= off) pincl += t;
    }
    uint32_t pexcl = pincl - ps;                    // digit base for this word pair
    uint32_t g0 = pexcl + (wexcl & 0xFFFFu);
    uint32_t g1 = pexcl + gl + (wexcl >> 16);
    WG[tid] = g0 | (g1 << 16);
  }
  __syncthreads();

  // exclusive within-thread base: WG + (inclusive h - own pre-scan counts),
  // pre-scan words recomputed from lo/hi (fewer live VGPRs across the scan)
  uint32_t p0 = WG[(wave << 2) + 0] + h[0] - ((lo & 0xFFu) | ((lo & 0xFF00u) << 8));
  uint32_t p1 = WG[(wave << 2) + 1] + h[1] - (((lo >> 16) & 0xFFu) | ((lo >> 24) << 16));
  uint32_t p2 = WG[(wave << 2) + 2] + h[2] - ((hi & 0xFFu) | ((hi & 0xFF00u) << 8));
  uint32_t p3 = WG[(wave << 2) + 3] + h[3] - (((hi >> 16) & 0xFFu) | ((hi >> 24) << 16));
  uint64_t pc0 = (uint64_t)p0 | ((uint64_t)p1 << 32);
  uint64_t pc1 = (uint64_t)p2 | ((uint64_t)p3 << 32);

#pragma unroll
  for (int e = 0; e < SE; e++) {
    uint32_t d = (k[e] >> sh) & 7u;
    uint32_t s16 = (d & 3u) << 4;
    bool lo4 = d < 4u;
    uint64_t t = lo4 ? pc0 : pc1;
    uint32_t pos = (uint32_t)(t >> s16) & 0xFFFFu;
    uint64_t inc = 1ull << s16;
    pc0 += lo4 ? inc : 0ull;
    pc1 += lo4 ? 0ull : inc;
    S[swz(pos)] = k[e];
  }
  __syncthreads();
}

__device__ __forceinline__ void radix18(uint32_t (&k)[SE], uint32_t* S,
                                        uint32_t* WG, int tid) {
  bool first = true;
  for (int sh = 14; sh < 32; sh += 3) {
    radix_pass(k, S, WG, tid, sh, first);
    first = false;
  }
}

// ---------- kernel 1: normalize theta -> bf16 thb [p][d] AND thbT [d][p] ----
__global__ void normalize_theta(const float* __restrict__ theta,
                                ushort* __restrict__ thb,
                                ushort* __restrict__ thbT) {
  const int p = blockIdx.x, t = threadIdx.x;
  ushort v16 = 0;
  if (p < NP) {
    float v = theta[p * ND + t];
    float ss = v * v;
#pragma unroll
    for (int off = 32; off >= 1; off >>= 1) ss += __shfl_xor(ss, off, 64);
    v16 = (ushort)bf16c(v * rsqrtf(ss));
  }
  thb[p * ND + t] = v16;
  thbT[t * NPP + p] = v16;
}

// ---------- kernel 2: MFMA projection (x AND y per block, LDS-staged) ------
// Stage the block's 64x64 fp32 tiles of x and y into LDS as bf16 via fully
// coalesced global loads (1KB/instr), then read MFMA A-fragments with
// ds_read_b128 (72-ushort padded rows -> 2-way bank aliasing = free).
__global__ __launch_bounds__(256) void project_mfma(
    const float* __restrict__ x, const float* __restrict__ y,
    const ushort* __restrict__ thb, float* __restrict__ xp,
    float* __restrict__ yp) {
  __shared__ ushort XT[64 * TROW];
  __shared__ ushort YT[64 * TROW];
  const int tid  = threadIdx.x;
  const int lane = tid & 63;
  const int quad = lane >> 4;
  const int mloc = lane & 15;
  const int wave = tid >> 6;

  const int m0 = blockIdx.x * 64 + wave * 16;   // 2048 blocks, 64 rows each
  const int b  = m0 >> 14;
  const int n0 = m0 & (NN - 1);

  // --- stage: 64 rows x 64 cols, 1024 float4 per matrix, 4 per thread ---
  {
    const float4* gx = (const float4*)(x + (long)blockIdx.x * 64 * ND);
    const float4* gy = (const float4*)(y + (long)blockIdx.x * 64 * ND);
#pragma unroll
    for (int i = 0; i < 4; i++) {
      const int f4 = tid + 256 * i;        // 0..1023
      const int row = f4 >> 4;             // 16 float4 per row
      const int c4  = f4 & 15;
      float4 vx = gx[f4];
      float4 vy = gy[f4];
      uint2 px, py;
      px.x = bf16pk(vx.x, vx.y); px.y = bf16pk(vx.z, vx.w);
      py.x = bf16pk(vy.x, vy.y); py.y = bf16pk(vy.z, vy.w);
      const int us = row * TROW + c4 * 4;  // ushort index, 8B-aligned
      *(uint2*)(XT + us) = px;
      *(uint2*)(YT + us) = py;
    }
  }
  __syncthreads();

  // --- fragments from LDS ---
  const int fr = wave * 16 + mloc;         // row within block tile
  const short8 ax0 = *(const short8*)(XT + fr * TROW + quad * 8);
  const short8 ax1 = *(const short8*)(XT + fr * TROW + 32 + quad * 8);
  const short8 ay0 = *(const short8*)(YT + fr * TROW + quad * 8);
  const short8 ay1 = *(const short8*)(YT + fr * TROW + 32 + quad * 8);

  const f32x4 zero = {0.f, 0.f, 0.f, 0.f};
#pragma unroll
  for (int t = 0; t < 7; t++) {
    const int p = t * 16 + mloc;
    const short8 b0 = *(const short8*)(thb + p * ND + quad * 8);
    const short8 b1 = *(const short8*)(thb + p * ND + 32 + quad * 8);
    f32x4 accx = __builtin_amdgcn_mfma_f32_16x16x32_bf16(ax0, b0, zero, 0, 0, 0);
    accx = __builtin_amdgcn_mfma_f32_16x16x32_bf16(ax1, b1, accx, 0, 0, 0);
    f32x4 accy = __builtin_amdgcn_mfma_f32_16x16x32_bf16(ay0, b0, zero, 0, 0, 0);
    accy = __builtin_amdgcn_mfma_f32_16x16x32_bf16(ay1, b1, accy, 0, 0, 0);
    if (t < 6 || mloc < (NP - 96)) {
      const long off = ((long)b * NP + p) * NN + n0 + quad * 4;
      *(f32x4*)(xp + off) = accx;   // rows quad*4+r are consecutive n -> float4
      *(f32x4*)(yp + off) = accy;
    }
  }
}

// ---------- kernel 3: per-(b,p) radix-sort y, rank x, write bf16 diff ------
// x_proj values kept in registers from the key-build phase (no tail re-read).
// diff is emitted as BF16 (the exact bf16c value combine would compute --
// bit-identical output) into the FIRST HALF of this block's own xp row span
// ((ushort*)xp, row stride 2*NN ushorts).  Safe: the block reads its fp32 xp
// row before writing; the span is block-private (project wrote it earlier,
// only combine reads it later); rows are 32KB contiguous, fully block-owned
// -> full-line writes, no cross-XCD false sharing (r6 lesson).
__global__ __launch_bounds__(ST, 8) void sort_diff_kernel(
    float* __restrict__ xp, const float* __restrict__ yp) {
  __shared__ uint32_t S[NN];    // 64 KB
  __shared__ uint32_t WG[64];
  const int tid = threadIdx.x;
  const long sbase = (long)blockIdx.x * NN;
  uint32_t k[SE];

  {
    const uint4* yg = (const uint4*)(yp + sbase) + (tid << 2);
#pragma unroll
    for (int q = 0; q < 4; q++) {
      uint4 v = yg[q];
      k[4 * q + 0] = f2s_u(v.x); k[4 * q + 1] = f2s_u(v.y);
      k[4 * q + 2] = f2s_u(v.z); k[4 * q + 3] = f2s_u(v.w);
    }
  }
  radix18(k, S, WG, tid);

  float ys[SE];
#pragma unroll
  for (int q = 0; q < 4; q++) {
    uint32_t wb = ((uint32_t)tid << 4) + ((uint32_t)q << 2);
    uint4 v = *(const uint4*)(S + (wb ^ ((wb >> 3) & 0x1Cu)));
    ys[4 * q + 0] = s2f(v.x); ys[4 * q + 1] = s2f(v.y);
    ys[4 * q + 2] = s2f(v.z); ys[4 * q + 3] = s2f(v.w);
  }

  float xs[SE];
  {
    const uint4* xg = (const uint4*)(xp + sbase) + (tid << 2);
#pragma unroll
    for (int q = 0; q < 4; q++) {
      uint4 v = xg[q];
      xs[4 * q + 0] = __uint_as_float(v.x);
      xs[4 * q + 1] = __uint_as_float(v.y);
      xs[4 * q + 2] = __uint_as_float(v.z);
      xs[4 * q + 3] = __uint_as_float(v.w);
      uint32_t g = ((uint32_t)tid << 4) + (uint32_t)(q << 2);
      k[4 * q + 0] = (f2s_u(v.x) & 0xFFFFC000u) | (g + 0);
      k[4 * q + 1] = (f2s_u(v.y) & 0xFFFFC000u) | (g + 1);
      k[4 * q + 2] = (f2s_u(v.z) & 0xFFFFC000u) | (g + 2);
      k[4 * q + 3] = (f2s_u(v.w) & 0xFFFFC000u) | (g + 3);
    }
  }
  radix18(k, S, WG, tid);

#pragma unroll
  for (int q = 0; q < 4; q++) {
    uint32_t wb = ((uint32_t)tid << 4) + ((uint32_t)q << 2);
    uint4 v = *(const uint4*)(S + (wb ^ ((wb >> 3) & 0x1Cu)));
    k[4 * q + 0] = v.x & 0x3FFFu; k[4 * q + 1] = v.y & 0x3FFFu;
    k[4 * q + 2] = v.z & 0x3FFFu; k[4 * q + 3] = v.w & 0x3FFFu;
  }
  __syncthreads();

#pragma unroll
  for (int e = 0; e < SE; e++) {
    S[swz(k[e])] = __float_as_uint(ys[e]);
  }
  __syncthreads();

  // bf16(transported - x_proj) into the block's own half-span
  ushort* drow = (ushort*)(xp + sbase);
#pragma unroll
  for (int q = 0; q < 4; q++) {
    uint32_t wb = ((uint32_t)tid << 4) + ((uint32_t)q << 2);
    uint4 v = *(const uint4*)(S + (wb ^ ((wb >> 3) & 0x1Cu)));
    uint2 pk;
    pk.x = bf16pk(__uint_as_float(v.x) - xs[4 * q + 0],
                  __uint_as_float(v.y) - xs[4 * q + 1]);
    pk.y = bf16pk(__uint_as_float(v.z) - xs[4 * q + 2],
                  __uint_as_float(v.w) - xs[4 * q + 3]);
    *(uint2*)(drow + wb) = pk;    // 8B-aligned, coalesced, block-owned lines
  }
}

// ---------- kernel 4: MFMA combine ----------
// A-frags: strided scalar ushort gather from bf16 diff living in the xp
// half-spans (row stride 2*NN ushorts).  L3-resident scattered loads at high
// occupancy measured FASTER than LDS staging (r9: +17us regression).
// B-frags: single contiguous short8 per (t,kf) from thbT [d][p].
__global__ __launch_bounds__(256) void combine_mfma(
    const float* __restrict__ x, const ushort* __restrict__ dT,
    const ushort* __restrict__ thbT, float* __restrict__ out) {
  const int tid  = threadIdx.x;
  const int lane = tid & 63;
  const int quad = lane >> 4;
  const int mloc = lane & 15;
  const int wave = tid >> 6;

  const int m0 = blockIdx.x * 64 + wave * 16;   // wave's first global row
  const int b  = m0 >> 14;
  const int n0 = m0 & (NN - 1);

  // row (b*NP+p) lives at ushort offset (b*NP+p)*2*NN (first half of span)
  const ushort* du = dT + (long)(b * NP) * (2 * NN) + n0 + mloc;
  short8 a[4];
#pragma unroll
  for (int kf = 0; kf < 4; kf++) {
#pragma unroll
    for (int j = 0; j < 8; j++) {
      const int p = kf * 32 + quad * 8 + j;
      a[kf][j] = (p < NP) ? (short)du[(long)p * (2 * NN)] : (short)0;
    }
  }

  const float inv = 1.0f / (float)NP;
  const f32x4 zero = {0.f, 0.f, 0.f, 0.f};
#pragma unroll
  for (int t = 0; t < 4; t++) {
    const int d = t * 16 + mloc;
    f32x4 acc = zero;
#pragma unroll
    for (int kf = 0; kf < 4; kf++) {
      const short8 bf = *(const short8*)(thbT + (long)d * NPP + kf * 32 + quad * 8);
      acc = __builtin_amdgcn_mfma_f32_16x16x32_bf16(a[kf], bf, acc, 0, 0, 0);
    }
#pragma unroll
    for (int r = 0; r < 4; r++) {
      const long off = (long)(m0 + quad * 4 + r) * ND + d;
      out[off] = x[off] + acc[r] * inv;
    }
  }
}

extern "C" void kernel_launch(void* const* d_in, const int* in_sizes, int n_in,
                              void* d_out, int out_size, void* d_ws, size_t ws_size,
                              hipStream_t stream) {
  const float* x     = (const float*)d_in[0];
  const float* y     = (const float*)d_in[1];
  const float* theta = (const float*)d_in[2];
  float* out = (float*)d_out;

  // workspace: [thb 16KB][thbT 16KB][xp 52.4MB][yp 52.4MB]
  // bf16 diff reuses the xp region (first half of each row's byte span).
  ushort* thb  = (ushort*)d_ws;
  ushort* thbT = thb + (size_t)NPP * ND;
  float* xp = (float*)((char*)d_ws + (1 << 15));
  float* yp = xp + (size_t)NB * NP * NN;

  normalize_theta<<<dim3(NPP), dim3(ND), 0, stream>>>(theta, thb, thbT);
  project_mfma<<<dim3((NB * NN) / 64), dim3(256), 0, stream>>>(x, y, thb, xp, yp);
  sort_diff_kernel<<<dim3(NB * NP), dim3(ST), 0, stream>>>(xp, yp);
  combine_mfma<<<dim3((NB * NN) / 64), dim3(256), 0, stream>>>(x, (const ushort*)xp, thbT, out);
}